// Round 6
// baseline (278.916 us; speedup 1.0000x reference)
//
// MPModule fused pipeline, round 21: mega-kernel via PLAIN launch.
// r19/r20 failed with IDENTICAL absmax (140.0 = max|ref| vs zeroed output):
// the cooperative launch never executed (cooperative launches are not
// stream-capturable; error code unchecked by harness). Same mega kernel,
// now a regular <<<256>>> launch. Co-residency by capacity arithmetic:
// __launch_bounds__(256,2) => 2 blocks/CU => capacity 512 >= grid 256, so
// ALL blocks resident regardless of placement (no deadlock). Phases are
// grid-strided: block b does units {b, b+256}; decode keeps B-panels shared
// across the two halves (L2-hot). Monotonic gbar (agent atomics +
// __threadfence -> buffer_wbl2/inv sc1) unchanged; P_T aliases d_out.
// Phases: cvt -> e_gemm -> atb -> reduce_g -> h_mfma -> out_gemm.
#include <hip/hip_runtime.h>

#define NE 8192
#define DD 256
#define NSPLIT 16
#define NBLK 256

typedef __attribute__((ext_vector_type(8))) short short8;
typedef __attribute__((ext_vector_type(4))) short short4v;
typedef __attribute__((ext_vector_type(8))) __bf16 bf16x8;
typedef __attribute__((ext_vector_type(4))) float floatx4;

__device__ __forceinline__ unsigned short f2bf(float f) {
  union { float f; unsigned int i; } v; v.f = f;
  unsigned int r = v.i + 0x7fffu + ((v.i >> 16) & 1u);
  return (unsigned short)(r >> 16);
}

__device__ __forceinline__ floatx4 mfma_bf16(short8 a, short8 b, floatx4 c) {
  return __builtin_amdgcn_mfma_f32_16x16x32_bf16(
      __builtin_bit_cast(bf16x8, a), __builtin_bit_cast(bf16x8, b), c, 0, 0, 0);
}

// Monotonic grid barrier (counter zeroed by captured hipMemsetAsync per
// launch). Release: __syncthreads drains each wave's vmem; thread0's
// agent fence writes back this XCD's L2. Acquire: agent fence invalidates
// L1/L2 before any thread's post-barrier loads (cache-scoped, so thread0's
// fence covers the whole CU).
__device__ __forceinline__ void gbar(unsigned* bar, unsigned target) {
  __syncthreads();
  if (threadIdx.x == 0) {
    __threadfence();
    __hip_atomic_fetch_add(bar, 1u, __ATOMIC_ACQ_REL, __HIP_MEMORY_SCOPE_AGENT);
    while (__hip_atomic_load(bar, __ATOMIC_ACQUIRE, __HIP_MEMORY_SCOPE_AGENT) < target)
      __builtin_amdgcn_s_sleep(1);
    __threadfence();
  }
  __syncthreads();
}

__device__ __forceinline__ void tcvt_tile(float* ls,
                                          const float* __restrict__ src, int C,
                                          unsigned short* __restrict__ dst, int R,
                                          int r0, int c0, int tid) {
  const int rr = tid >> 4, c4 = (tid & 15) * 4;
#pragma unroll
  for (int k = 0; k < 4; ++k)
    *(floatx4*)&ls[(rr + k * 16) * 68 + c4] =
        *(const floatx4*)&src[(size_t)(r0 + rr + k * 16) * C + c0 + c4];
  __syncthreads();
  const int cc = tid >> 2, rb = (tid & 3) * 16;
  short8 o0, o1;
#pragma unroll
  for (int i = 0; i < 8; ++i) {
    o0[i] = (short)f2bf(ls[(rb + i) * 68 + cc]);
    o1[i] = (short)f2bf(ls[(rb + 8 + i) * 68 + cc]);
  }
  unsigned short* dp = &dst[(size_t)(c0 + cc) * R + r0 + rb];
  *(short8*)dp = o0;
  *(short8*)(dp + 8) = o1;
}

__global__ __launch_bounds__(256, 2)
void mega(const float* __restrict__ x,
          const float* __restrict__ W1, const float* __restrict__ b1,
          const float* __restrict__ W2, const float* __restrict__ b2,
          const float* __restrict__ W3, const float* __restrict__ b3,
          float* __restrict__ out,
          unsigned short* __restrict__ xb, unsigned short* __restrict__ xT,
          unsigned short* __restrict__ e1, unsigned short* __restrict__ e2,
          unsigned short* __restrict__ e1T, unsigned short* __restrict__ e2T,
          unsigned short* __restrict__ W1t, unsigned short* __restrict__ W2t,
          unsigned short* __restrict__ W3t0,
          unsigned short* __restrict__ H1t, unsigned short* __restrict__ H2t,
          float* __restrict__ G_T, float* __restrict__ P_T,
          unsigned* bar)
{
  __shared__ __align__(16) unsigned short smPool[3 * 64 * 136];  // 52,224 B
  unsigned short* smA  = smPool;
  unsigned short* smB1 = smPool + 64 * 136;
  unsigned short* smB2 = smPool + 2 * 64 * 136;
  const int b = blockIdx.x, T = threadIdx.x;
  const int lane = T & 63, wv = T >> 6;
  const int q = lane >> 4, r = lane & 15;

  // ===== phase 1: conversions. Units b and b+256; blocks 0..47 also weights.
  {
    float* ls = (float*)smPool;
#pragma unroll
    for (int h = 0; h < 2; ++h) {
      const int L = b + h * NBLK;
      const int p = L & 7, k = L >> 3;
      const int r0 = (16 * p + (k >> 2)) * 64, c0 = (k & 3) * 64;
      const int rr = T >> 4, c4 = (T & 15) * 4;
#pragma unroll
      for (int kk = 0; kk < 4; ++kk) {
        floatx4 v = *(const floatx4*)&x[(size_t)(r0 + rr + kk * 16) * DD + c0 + c4];
        *(floatx4*)&ls[(rr + kk * 16) * 68 + c4] = v;
        short4v s;
#pragma unroll
        for (int c = 0; c < 4; ++c) s[c] = (short)f2bf(v[c]);
        *(short4v*)&xb[(size_t)(r0 + rr + kk * 16) * DD + c0 + c4] = s;
      }
      __syncthreads();
      const int cc = T >> 2, rb = (T & 3) * 16;
      short8 o0, o1;
#pragma unroll
      for (int i = 0; i < 8; ++i) {
        o0[i] = (short)f2bf(ls[(rb + i) * 68 + cc]);
        o1[i] = (short)f2bf(ls[(rb + 8 + i) * 68 + cc]);
      }
      unsigned short* dp = &xT[(size_t)(c0 + cc) * NE + r0 + rb];
      *(short8*)dp = o0;
      *(short8*)(dp + 8) = o1;
      __syncthreads();  // ls reused next half / by weight tile
    }
    if (b < 48) {
      int t = b;
      const float* src = (t < 16) ? W1 : ((t < 32) ? W2 : W3);
      unsigned short* dst = (t < 16) ? W1t : ((t < 32) ? W2t : W3t0);
      t &= 15;
      tcvt_tile(ls, src, DD, dst, DD, (t >> 2) * 64, (t & 3) * 64, T);
    }
  }
  gbar(bar, 1 * NBLK);

  // ===== phase 2: e_gemm. Units b and b+256 (same cols, rows +512 apart).
#pragma unroll 1
  for (int h = 0; h < 2; ++h) {
    const int L = b + h * NBLK;
    const int p = L & 7, k = L >> 3;
    const int col0 = (k & 3) * 64, row0 = (16 * p + (k >> 2)) * 64;

    floatx4 acc1[4], acc2[4];
#pragma unroll
    for (int j = 0; j < 4; ++j) {
      acc1[j] = (floatx4){0.f, 0.f, 0.f, 0.f};
      acc2[j] = (floatx4){0.f, 0.f, 0.f, 0.f};
    }

    short8 pa[4], pb1[4], pb2[4];
#pragma unroll
    for (int pp = 0; pp < 4; ++pp) {
      const int id = pp * 256 + T, rr = id >> 4, k8 = (id & 15) * 8;
      pa[pp]  = *(const short8*)&xb[(size_t)(row0 + rr) * DD + k8];
      pb1[pp] = *(const short8*)&W1t[(size_t)(col0 + rr) * DD + k8];
      pb2[pp] = *(const short8*)&W2t[(size_t)(col0 + rr) * DD + k8];
    }

    for (int kc = 0; kc < 256; kc += 128) {
#pragma unroll
      for (int pp = 0; pp < 4; ++pp) {
        const int id = pp * 256 + T, rr = id >> 4, k8 = (id & 15) * 8;
        *(short8*)&smA[rr * 136 + k8]  = pa[pp];
        *(short8*)&smB1[rr * 136 + k8] = pb1[pp];
        *(short8*)&smB2[rr * 136 + k8] = pb2[pp];
      }
      __syncthreads();
      if (kc + 128 < 256) {
#pragma unroll
        for (int pp = 0; pp < 4; ++pp) {
          const int id = pp * 256 + T, rr = id >> 4, k8 = (id & 15) * 8;
          pa[pp]  = *(const short8*)&xb[(size_t)(row0 + rr) * DD + kc + 128 + k8];
          pb1[pp] = *(const short8*)&W1t[(size_t)(col0 + rr) * DD + kc + 128 + k8];
          pb2[pp] = *(const short8*)&W2t[(size_t)(col0 + rr) * DD + kc + 128 + k8];
        }
      }
#pragma unroll
      for (int ks = 0; ks < 4; ++ks) {
        short8 af = *(const short8*)&smA[(wv * 16 + r) * 136 + ks * 32 + q * 8];
#pragma unroll
        for (int j = 0; j < 4; ++j) {
          short8 b1f = *(const short8*)&smB1[(j * 16 + r) * 136 + ks * 32 + q * 8];
          short8 b2f = *(const short8*)&smB2[(j * 16 + r) * 136 + ks * 32 + q * 8];
          acc1[j] = mfma_bf16(af, b1f, acc1[j]);
          acc2[j] = mfma_bf16(af, b2f, acc2[j]);
        }
      }
      __syncthreads();
    }

    unsigned short* t1s = smB1;
    unsigned short* t2s = smB2;
#pragma unroll
    for (int j = 0; j < 4; ++j) {
      const int col = col0 + j * 16 + r;
      const int lc = j * 16 + r;
      const int lr = wv * 16 + q * 4;
      const int rowb = row0 + lr;
      const float b1v = b1[col], b2v = b2[col];
#pragma unroll
      for (int t = 0; t < 4; ++t) {
        unsigned short h1 = f2bf(fmaxf(acc1[j][t] + b1v, 0.0f));
        unsigned short h2 = f2bf(fmaxf(acc2[j][t] + b2v, 0.0f));
        t1s[lc * 68 + lr + t] = h1;
        t2s[lc * 68 + lr + t] = h2;
        e1[(size_t)(rowb + t) * DD + col] = h1;
        e2[(size_t)(rowb + t) * DD + col] = h2;
      }
    }
    __syncthreads();
    {
      const int c = T >> 2, seg = (T & 3) * 16;
      short8 v1a = *(short8*)&t1s[c * 68 + seg];
      short8 v1b = *(short8*)&t1s[c * 68 + seg + 8];
      short8 v2a = *(short8*)&t2s[c * 68 + seg];
      short8 v2b = *(short8*)&t2s[c * 68 + seg + 8];
      unsigned short* d1 = &e1T[(size_t)(col0 + c) * NE + row0 + seg];
      unsigned short* d2 = &e2T[(size_t)(col0 + c) * NE + row0 + seg];
      *(short8*)d1 = v1a; *(short8*)(d1 + 8) = v1b;
      *(short8*)d2 = v2a; *(short8*)(d2 + 8) = v2b;
    }
    __syncthreads();  // t1s/t2s (smB1/smB2) reused by next half's staging
  }
  gbar(bar, 2 * NBLK);

  // ===== phase 3: atb. Units b and b+256 (z flips, same (mn,y) -> xT hot).
#pragma unroll 1
  for (int h = 0; h < 2; ++h) {
    const int L = b + h * NBLK;
    const int p = L & 7, k = L >> 3;
    const int y = 2 * p + (k & 1);
    const int t2 = k >> 1;
    const int mn = t2 & 15, z = t2 >> 4;
    const int m0 = (mn >> 2) * 64, n0 = (mn & 3) * 64;
    const int j0 = y * (NE / NSPLIT);
    const unsigned short* E = z ? e2T : e1T;
    float* P = P_T + (size_t)(z * NSPLIT + y) * 65536;

    floatx4 acc[4];
#pragma unroll
    for (int j = 0; j < 4; ++j) acc[j] = (floatx4){0.f, 0.f, 0.f, 0.f};

    short8 pa[4], pb[4];
#pragma unroll
    for (int pp = 0; pp < 4; ++pp) {
      const int id = pp * 256 + T, mm = id >> 4, j8 = (id & 15) * 8;
      pa[pp] = *(const short8*)&E[(size_t)(m0 + mm) * NE + j0 + j8];
      pb[pp] = *(const short8*)&xT[(size_t)(n0 + mm) * NE + j0 + j8];
    }

    for (int jc = 0; jc < NE / NSPLIT; jc += 128) {
#pragma unroll
      for (int pp = 0; pp < 4; ++pp) {
        const int id = pp * 256 + T, mm = id >> 4, j8 = (id & 15) * 8;
        *(short8*)&smA[mm * 136 + j8] = pa[pp];
        *(short8*)&smB1[mm * 136 + j8] = pb[pp];
      }
      __syncthreads();
      if (jc + 128 < NE / NSPLIT) {
#pragma unroll
        for (int pp = 0; pp < 4; ++pp) {
          const int id = pp * 256 + T, mm = id >> 4, j8 = (id & 15) * 8;
          pa[pp] = *(const short8*)&E[(size_t)(m0 + mm) * NE + j0 + jc + 128 + j8];
          pb[pp] = *(const short8*)&xT[(size_t)(n0 + mm) * NE + j0 + jc + 128 + j8];
        }
      }
#pragma unroll
      for (int ks = 0; ks < 4; ++ks) {
        short8 af = *(const short8*)&smA[(wv * 16 + r) * 136 + ks * 32 + q * 8];
#pragma unroll
        for (int j = 0; j < 4; ++j) {
          short8 bf = *(const short8*)&smB1[(j * 16 + r) * 136 + ks * 32 + q * 8];
          acc[j] = mfma_bf16(af, bf, acc[j]);
        }
      }
      __syncthreads();
    }
#pragma unroll
    for (int j = 0; j < 4; ++j) {
      const int n = n0 + j * 16 + r;
      const int m = m0 + wv * 16 + q * 4;
      *(floatx4*)&P[(size_t)n * DD + m] = acc[j];
    }
  }
  gbar(bar, 3 * NBLK);

  // ===== phase 4: reduce_g (blocks 0..127)
  if (b < 128) {
    int idx = b * 256 + T;
    int z = idx >> 14, off = idx & 16383;
    const floatx4* Pp = (const floatx4*)P_T;
    floatx4 s = (floatx4){0.f, 0.f, 0.f, 0.f};
#pragma unroll
    for (int y = 0; y < NSPLIT; ++y)
      s += Pp[(size_t)(z * NSPLIT + y) * 16384 + off];
    ((floatx4*)G_T)[idx] = s;
  }
  gbar(bar, 4 * NBLK);

  // ===== phase 5: h_mfma (blocks 0..31)
  if (b < 32) {
    const int z = b >> 4, bx = b & 15;
    const int me0 = (bx >> 2) * 64, m30 = (bx & 3) * 64;
    const float* G = G_T + (size_t)z * 65536;
    unsigned short* Ht = z ? H2t : H1t;
    const int woff = 256 + z * 256;

    floatx4 acc[4];
#pragma unroll
    for (int j = 0; j < 4; ++j) acc[j] = (floatx4){0.f, 0.f, 0.f, 0.f};

    for (int lc = 0; lc < 256; lc += 128) {
#pragma unroll
      for (int pp = 0; pp < 2; ++pp) {
        const int id = pp * 256 + T, lb = id >> 4, e4 = id & 15;
        floatx4 grow[4], wrow[4];
#pragma unroll
        for (int i = 0; i < 4; ++i) {
          grow[i] = *(const floatx4*)&G[(size_t)(lc + lb * 4 + i) * DD + me0 + e4 * 4];
          wrow[i] = *(const floatx4*)&W3[(size_t)(woff + lc + lb * 4 + i) * DD + m30 + e4 * 4];
        }
#pragma unroll
        for (int s4 = 0; s4 < 4; ++s4) {
          const int c = (s4 + e4) & 3;
          short4v ga = {(short)f2bf(grow[0][c] * 0.00390625f),
                        (short)f2bf(grow[1][c] * 0.00390625f),
                        (short)f2bf(grow[2][c] * 0.00390625f),
                        (short)f2bf(grow[3][c] * 0.00390625f)};
          short4v wa = {(short)f2bf(wrow[0][c]), (short)f2bf(wrow[1][c]),
                        (short)f2bf(wrow[2][c]), (short)f2bf(wrow[3][c])};
          *(short4v*)&smA[(e4 * 4 + c) * 136 + lb * 4] = ga;
          *(short4v*)&smB1[(e4 * 4 + c) * 136 + lb * 4] = wa;
        }
      }
      __syncthreads();
#pragma unroll
      for (int ks = 0; ks < 4; ++ks) {
        short8 af = *(const short8*)&smA[(wv * 16 + r) * 136 + ks * 32 + q * 8];
#pragma unroll
        for (int j = 0; j < 4; ++j) {
          short8 bf = *(const short8*)&smB1[(j * 16 + r) * 136 + ks * 32 + q * 8];
          acc[j] = mfma_bf16(af, bf, acc[j]);
        }
      }
      __syncthreads();
    }
#pragma unroll
    for (int j = 0; j < 4; ++j) {
      const int m3 = m30 + j * 16 + r;
      const int me = me0 + wv * 16 + q * 4;
      short4v v;
#pragma unroll
      for (int i = 0; i < 4; ++i) v[i] = (short)f2bf(acc[j][i]);
      *(short4v*)&Ht[(size_t)m3 * DD + me] = v;
    }
  }
  gbar(bar, 5 * NBLK);

  // ===== phase 6: out_gemm (fully overwrites `out`, which P_T aliased)
#pragma unroll 1
  for (int h = 0; h < 2; ++h) {
    const int L = b + h * NBLK;
    const int p = L & 7, k = L >> 3;
    const int col0 = (k & 3) * 64, row0 = (16 * p + (k >> 2)) * 64;

    const unsigned short* As[3] = {xb, e1, e2};
    const unsigned short* Bs[3] = {W3t0, H1t, H2t};

    floatx4 acc[4];
#pragma unroll
    for (int j = 0; j < 4; ++j) acc[j] = (floatx4){0.f, 0.f, 0.f, 0.f};

    short8 qa[4], qb[4];
#pragma unroll
    for (int pp = 0; pp < 4; ++pp) {
      const int id = pp * 256 + T, rr = id >> 4, k8 = (id & 15) * 8;
      qa[pp] = *(const short8*)&As[0][(size_t)(row0 + rr) * DD + k8];
      qb[pp] = *(const short8*)&Bs[0][(size_t)(col0 + rr) * DD + k8];
    }

    for (int rd = 0; rd < 6; ++rd) {
#pragma unroll
      for (int pp = 0; pp < 4; ++pp) {
        const int id = pp * 256 + T, rr = id >> 4, k8 = (id & 15) * 8;
        *(short8*)&smA[rr * 136 + k8] = qa[pp];
        *(short8*)&smB1[rr * 136 + k8] = qb[pp];
      }
      __syncthreads();
      if (rd + 1 < 6) {
        const int s = (rd + 1) >> 1, kc = ((rd + 1) & 1) * 128;
        const unsigned short* A = As[s];
        const unsigned short* B = Bs[s];
#pragma unroll
        for (int pp = 0; pp < 4; ++pp) {
          const int id = pp * 256 + T, rr = id >> 4, k8 = (id & 15) * 8;
          qa[pp] = *(const short8*)&A[(size_t)(row0 + rr) * DD + kc + k8];
          qb[pp] = *(const short8*)&B[(size_t)(col0 + rr) * DD + kc + k8];
        }
      }
#pragma unroll
      for (int ks = 0; ks < 4; ++ks) {
        short8 af = *(const short8*)&smA[(wv * 16 + r) * 136 + ks * 32 + q * 8];
#pragma unroll
        for (int j = 0; j < 4; ++j) {
          short8 bf = *(const short8*)&smB1[(j * 16 + r) * 136 + ks * 32 + q * 8];
          acc[j] = mfma_bf16(af, bf, acc[j]);
        }
      }
      __syncthreads();
    }
#pragma unroll
    for (int j = 0; j < 4; ++j) {
      const int col = col0 + j * 16 + r;
      const float bv = b3[col];
      const int rowb = row0 + wv * 16 + q * 4;
#pragma unroll
      for (int t = 0; t < 4; ++t)
        out[(size_t)(rowb + t) * DD + col] = fmaxf(acc[j][t] + bv, 0.0f);
    }
  }
}

// ---------------------------------------------------------------------------
extern "C" void kernel_launch(void* const* d_in, const int* in_sizes, int n_in,
                              void* d_out, int out_size, void* d_ws, size_t ws_size,
                              hipStream_t stream) {
  (void)in_sizes; (void)n_in; (void)out_size; (void)ws_size;
  const float* x  = (const float*)d_in[3];
  const float* W1 = (const float*)d_in[5];
  const float* b1 = (const float*)d_in[6];
  const float* W2 = (const float*)d_in[7];
  const float* b2 = (const float*)d_in[8];
  const float* W3 = (const float*)d_in[9];
  const float* b3 = (const float*)d_in[10];
  float* out = (float*)d_out;

  char* ws = (char*)d_ws;
  const size_t MB = 1u << 20;
  const size_t KB = 1u << 10;
  unsigned short* xb   = (unsigned short*)ws;                          // 4 MB
  unsigned short* xT   = (unsigned short*)(ws + 4 * MB);               // 4 MB
  unsigned short* e1   = (unsigned short*)(ws + 8 * MB);               // 4 MB
  unsigned short* e2   = (unsigned short*)(ws + 12 * MB);              // 4 MB
  unsigned short* e1T  = (unsigned short*)(ws + 16 * MB);              // 4 MB
  unsigned short* e2T  = (unsigned short*)(ws + 20 * MB);              // 4 MB
  unsigned short* W1t  = (unsigned short*)(ws + 24 * MB);              // 128 KB
  unsigned short* W2t  = (unsigned short*)(ws + 24 * MB + 128 * KB);   // 128 KB
  unsigned short* W3t0 = (unsigned short*)(ws + 24 * MB + 256 * KB);   // 128 KB
  unsigned short* H1t  = (unsigned short*)(ws + 24 * MB + 384 * KB);   // 128 KB
  unsigned short* H2t  = (unsigned short*)(ws + 24 * MB + 512 * KB);   // 128 KB
  float* G_T           = (float*)(ws + 24 * MB + 640 * KB);            // 512 KB -> ends 24MB+1152KB
  unsigned* bar        = (unsigned*)(ws + 24 * MB + 1152 * KB);        // 128 B, in-bounds
  float* P_T           = (float*)d_out;                                // 8 MB scratch, dead until phase 6

  hipMemsetAsync(bar, 0, 128, stream);

  mega<<<NBLK, 256, 0, stream>>>(x, W1, b1, W2, b2, W3, b3, out,
                                 xb, xT, e1, e2, e1T, e2T, W1t, W2t, W3t0,
                                 H1t, H2t, G_T, P_T, bar);
}

// Round 7
// 121.681 us; speedup vs baseline: 2.2922x; 2.2922x over previous
//
// MPModule fused pipeline, round 22: revert mega (r21: 279us, occupancy
// collapse + barrier spin). Base = round 18 (120.4us best). NEW: atb is
// z-MERGED (one block computes G1 AND G2 partials, sharing the xT panel
// read: 64->48 MB) with NSPLIT=32 (j-span 256, 2 rounds) and bf16 P_T
// partials (8 MB unchanged footprint, half the write+reduce traffic;
// error ~0.1 on G std ~50, negligible after /256 + bf16 rounding).
// Structure: cvt_all -> e_gemm -> atb -> reduce_g -> h_mfma -> out_gemm.
#include <hip/hip_runtime.h>

#define NE 8192
#define DD 256
#define NSPLIT 32

typedef __attribute__((ext_vector_type(8))) short short8;
typedef __attribute__((ext_vector_type(4))) short short4v;
typedef __attribute__((ext_vector_type(8))) __bf16 bf16x8;
typedef __attribute__((ext_vector_type(4))) float floatx4;

__device__ __forceinline__ unsigned short f2bf(float f) {
  union { float f; unsigned int i; } v; v.f = f;
  unsigned int r = v.i + 0x7fffu + ((v.i >> 16) & 1u);
  return (unsigned short)(r >> 16);
}

__device__ __forceinline__ float bf2f(unsigned short h) {
  union { unsigned int i; float f; } v; v.i = ((unsigned int)h) << 16;
  return v.f;
}

__device__ __forceinline__ floatx4 mfma_bf16(short8 a, short8 b, floatx4 c) {
  return __builtin_amdgcn_mfma_f32_16x16x32_bf16(
      __builtin_bit_cast(bf16x8, a), __builtin_bit_cast(bf16x8, b), c, 0, 0, 0);
}

// ---------------------------------------------------------------------------
// K0: conversions, x read ONCE. Blocks [0,512): one 64x64 x-tile -> xb
// (row-major bf16) AND xT (transposed bf16); block id swizzled so row-chunk
// [1024p,1024p+1024) has id%8==p (XCD p). [512,560): W1/W2/W3a transpose.
__device__ __forceinline__ void tcvt_tile(float* ls,
                                          const float* __restrict__ src, int C,
                                          unsigned short* __restrict__ dst, int R,
                                          int r0, int c0, int tid) {
  const int rr = tid >> 4, c4 = (tid & 15) * 4;
#pragma unroll
  for (int k = 0; k < 4; ++k)
    *(floatx4*)&ls[(rr + k * 16) * 68 + c4] =
        *(const floatx4*)&src[(size_t)(r0 + rr + k * 16) * C + c0 + c4];
  __syncthreads();
  const int cc = tid >> 2, rb = (tid & 3) * 16;
  short8 o0, o1;
#pragma unroll
  for (int i = 0; i < 8; ++i) {
    o0[i] = (short)f2bf(ls[(rb + i) * 68 + cc]);
    o1[i] = (short)f2bf(ls[(rb + 8 + i) * 68 + cc]);
  }
  unsigned short* dp = &dst[(size_t)(c0 + cc) * R + r0 + rb];
  *(short8*)dp = o0;
  *(short8*)(dp + 8) = o1;
}

__global__ void cvt_all(const float* __restrict__ x, unsigned short* __restrict__ xb,
                        unsigned short* __restrict__ xT,
                        const float* __restrict__ W1, unsigned short* __restrict__ W1t,
                        const float* __restrict__ W2, unsigned short* __restrict__ W2t,
                        const float* __restrict__ W3, unsigned short* __restrict__ W3t0) {
  __shared__ float ls[64 * 68];
  const int b = blockIdx.x, tid = threadIdx.x;
  if (b < 512) {
    const int p = b & 7, k = b >> 3;
    const int r0 = (16 * p + (k >> 2)) * 64, c0 = (k & 3) * 64;
    const int rr = tid >> 4, c4 = (tid & 15) * 4;
#pragma unroll
    for (int kk = 0; kk < 4; ++kk) {
      floatx4 v = *(const floatx4*)&x[(size_t)(r0 + rr + kk * 16) * DD + c0 + c4];
      *(floatx4*)&ls[(rr + kk * 16) * 68 + c4] = v;
      short4v s;
#pragma unroll
      for (int c = 0; c < 4; ++c) s[c] = (short)f2bf(v[c]);
      *(short4v*)&xb[(size_t)(r0 + rr + kk * 16) * DD + c0 + c4] = s;
    }
    __syncthreads();
    const int cc = tid >> 2, rb = (tid & 3) * 16;
    short8 o0, o1;
#pragma unroll
    for (int i = 0; i < 8; ++i) {
      o0[i] = (short)f2bf(ls[(rb + i) * 68 + cc]);
      o1[i] = (short)f2bf(ls[(rb + 8 + i) * 68 + cc]);
    }
    unsigned short* dp = &xT[(size_t)(c0 + cc) * NE + r0 + rb];
    *(short8*)dp = o0;
    *(short8*)(dp + 8) = o1;
  } else {
    int t = b - 512;
    const float* src = (t < 16) ? W1 : ((t < 32) ? W2 : W3);
    unsigned short* dst = (t < 16) ? W1t : ((t < 32) ? W2t : W3t0);
    t &= 15;
    tcvt_tile(ls, src, DD, dst, DD, (t >> 2) * 64, (t & 3) * 64, tid);
  }
}

// ---------------------------------------------------------------------------
// K1: e1 AND e2 from one block, reg-prefetch pipelined. Tile 64x64, BK=128
// (2 rounds). 512 blocks 1-D, LDS 52,224 B -> 3 blocks/CU.
__global__ __launch_bounds__(256, 3)
void e_gemm(const unsigned short* __restrict__ xb,
            const unsigned short* __restrict__ W1t, const float* __restrict__ b1,
            const unsigned short* __restrict__ W2t, const float* __restrict__ b2,
            unsigned short* __restrict__ e1, unsigned short* __restrict__ e2,
            unsigned short* __restrict__ e1T, unsigned short* __restrict__ e2T)
{
  __shared__ __align__(16) unsigned short smA[64 * 136];
  __shared__ __align__(16) unsigned short smB1[64 * 136];
  __shared__ __align__(16) unsigned short smB2[64 * 136];
  const int T = threadIdx.x, lane = T & 63, wv = T >> 6;
  const int q = lane >> 4, r = lane & 15;
  const int L = blockIdx.x;
  const int p = L & 7, k = L >> 3;
  const int col0 = (k & 3) * 64, row0 = (16 * p + (k >> 2)) * 64;

  floatx4 acc1[4], acc2[4];
#pragma unroll
  for (int j = 0; j < 4; ++j) {
    acc1[j] = (floatx4){0.f, 0.f, 0.f, 0.f};
    acc2[j] = (floatx4){0.f, 0.f, 0.f, 0.f};
  }

  short8 pa[4], pb1[4], pb2[4];
#pragma unroll
  for (int pp = 0; pp < 4; ++pp) {
    const int id = pp * 256 + T, rr = id >> 4, k8 = (id & 15) * 8;
    pa[pp]  = *(const short8*)&xb[(size_t)(row0 + rr) * DD + k8];
    pb1[pp] = *(const short8*)&W1t[(size_t)(col0 + rr) * DD + k8];
    pb2[pp] = *(const short8*)&W2t[(size_t)(col0 + rr) * DD + k8];
  }

  for (int kc = 0; kc < 256; kc += 128) {
#pragma unroll
    for (int pp = 0; pp < 4; ++pp) {
      const int id = pp * 256 + T, rr = id >> 4, k8 = (id & 15) * 8;
      *(short8*)&smA[rr * 136 + k8]  = pa[pp];
      *(short8*)&smB1[rr * 136 + k8] = pb1[pp];
      *(short8*)&smB2[rr * 136 + k8] = pb2[pp];
    }
    __syncthreads();
    if (kc + 128 < 256) {
#pragma unroll
      for (int pp = 0; pp < 4; ++pp) {
        const int id = pp * 256 + T, rr = id >> 4, k8 = (id & 15) * 8;
        pa[pp]  = *(const short8*)&xb[(size_t)(row0 + rr) * DD + kc + 128 + k8];
        pb1[pp] = *(const short8*)&W1t[(size_t)(col0 + rr) * DD + kc + 128 + k8];
        pb2[pp] = *(const short8*)&W2t[(size_t)(col0 + rr) * DD + kc + 128 + k8];
      }
    }
#pragma unroll
    for (int ks = 0; ks < 4; ++ks) {
      short8 af = *(const short8*)&smA[(wv * 16 + r) * 136 + ks * 32 + q * 8];
#pragma unroll
      for (int j = 0; j < 4; ++j) {
        short8 b1f = *(const short8*)&smB1[(j * 16 + r) * 136 + ks * 32 + q * 8];
        short8 b2f = *(const short8*)&smB2[(j * 16 + r) * 136 + ks * 32 + q * 8];
        acc1[j] = mfma_bf16(af, b1f, acc1[j]);
        acc2[j] = mfma_bf16(af, b2f, acc2[j]);
      }
    }
    __syncthreads();
  }

  unsigned short* t1s = smB1;
  unsigned short* t2s = smB2;
#pragma unroll
  for (int j = 0; j < 4; ++j) {
    const int col = col0 + j * 16 + r;
    const int lc = j * 16 + r;
    const int lr = wv * 16 + q * 4;
    const int rowb = row0 + lr;
    const float b1v = b1[col], b2v = b2[col];
#pragma unroll
    for (int t = 0; t < 4; ++t) {
      unsigned short h1 = f2bf(fmaxf(acc1[j][t] + b1v, 0.0f));
      unsigned short h2 = f2bf(fmaxf(acc2[j][t] + b2v, 0.0f));
      t1s[lc * 68 + lr + t] = h1;
      t2s[lc * 68 + lr + t] = h2;
      e1[(size_t)(rowb + t) * DD + col] = h1;
      e2[(size_t)(rowb + t) * DD + col] = h2;
    }
  }
  __syncthreads();
  {
    const int c = T >> 2, seg = (T & 3) * 16;
    short8 v1a = *(short8*)&t1s[c * 68 + seg];
    short8 v1b = *(short8*)&t1s[c * 68 + seg + 8];
    short8 v2a = *(short8*)&t2s[c * 68 + seg];
    short8 v2b = *(short8*)&t2s[c * 68 + seg + 8];
    unsigned short* d1 = &e1T[(size_t)(col0 + c) * NE + row0 + seg];
    unsigned short* d2 = &e2T[(size_t)(col0 + c) * NE + row0 + seg];
    *(short8*)d1 = v1a; *(short8*)(d1 + 8) = v1b;
    *(short8*)d2 = v2a; *(short8*)(d2 + 8) = v2b;
  }
}

// ---------------------------------------------------------------------------
// K2: z-MERGED split-K partials of G1 = e1T x and G2 = e2T x. One block
// loads E1, E2, xT panels (xT shared between both accumulations: reads
// 64->48 MB) and writes bf16 partials P[(z*32+y)][n][m]. NSPLIT=32: j-span
// 256, 2 rounds of 128. grid 512 1-D, XCD-affine (y chunks 4p..4p+3 on
// XCD p match e_gemm's production). LDS 3x[64][136] -> 3 blocks/CU.
__global__ __launch_bounds__(256, 3)
void atb(const unsigned short* __restrict__ e1T, const unsigned short* __restrict__ e2T,
         const unsigned short* __restrict__ xT, unsigned short* __restrict__ P_T)
{
  __shared__ __align__(16) unsigned short smE1[64 * 136];
  __shared__ __align__(16) unsigned short smE2[64 * 136];
  __shared__ __align__(16) unsigned short smX[64 * 136];
  const int T = threadIdx.x, lane = T & 63, wv = T >> 6;
  const int q = lane >> 4, r = lane & 15;
  const int L = blockIdx.x;
  const int p = L & 7, k = L >> 3;          // k in [0,64)
  const int mn = k >> 2;                    // [0,16)
  const int y = 4 * p + (k & 3);            // [0,32), XCD-affine
  const int m0 = (mn >> 2) * 64, n0 = (mn & 3) * 64;
  const int j0 = y * (NE / NSPLIT);         // chunk of 256

  floatx4 acc1[4], acc2[4];
#pragma unroll
  for (int j = 0; j < 4; ++j) {
    acc1[j] = (floatx4){0.f, 0.f, 0.f, 0.f};
    acc2[j] = (floatx4){0.f, 0.f, 0.f, 0.f};
  }

  short8 pe1[4], pe2[4], px[4];
#pragma unroll
  for (int pp = 0; pp < 4; ++pp) {
    const int id = pp * 256 + T, mm = id >> 4, j8 = (id & 15) * 8;
    pe1[pp] = *(const short8*)&e1T[(size_t)(m0 + mm) * NE + j0 + j8];
    pe2[pp] = *(const short8*)&e2T[(size_t)(m0 + mm) * NE + j0 + j8];
    px[pp]  = *(const short8*)&xT[(size_t)(n0 + mm) * NE + j0 + j8];
  }

  for (int jc = 0; jc < NE / NSPLIT; jc += 128) {
#pragma unroll
    for (int pp = 0; pp < 4; ++pp) {
      const int id = pp * 256 + T, mm = id >> 4, j8 = (id & 15) * 8;
      *(short8*)&smE1[mm * 136 + j8] = pe1[pp];
      *(short8*)&smE2[mm * 136 + j8] = pe2[pp];
      *(short8*)&smX[mm * 136 + j8]  = px[pp];
    }
    __syncthreads();
    if (jc + 128 < NE / NSPLIT) {
#pragma unroll
      for (int pp = 0; pp < 4; ++pp) {
        const int id = pp * 256 + T, mm = id >> 4, j8 = (id & 15) * 8;
        pe1[pp] = *(const short8*)&e1T[(size_t)(m0 + mm) * NE + j0 + jc + 128 + j8];
        pe2[pp] = *(const short8*)&e2T[(size_t)(m0 + mm) * NE + j0 + jc + 128 + j8];
        px[pp]  = *(const short8*)&xT[(size_t)(n0 + mm) * NE + j0 + jc + 128 + j8];
      }
    }
#pragma unroll
    for (int ks = 0; ks < 4; ++ks) {
      short8 a1 = *(const short8*)&smE1[(wv * 16 + r) * 136 + ks * 32 + q * 8];
      short8 a2 = *(const short8*)&smE2[(wv * 16 + r) * 136 + ks * 32 + q * 8];
#pragma unroll
      for (int j = 0; j < 4; ++j) {
        short8 bx = *(const short8*)&smX[(j * 16 + r) * 136 + ks * 32 + q * 8];
        acc1[j] = mfma_bf16(a1, bx, acc1[j]);
        acc2[j] = mfma_bf16(a2, bx, acc2[j]);
      }
    }
    __syncthreads();
  }

  // bf16 partial write: P[(z*32+y)][n*256+m]
#pragma unroll
  for (int j = 0; j < 4; ++j) {
    const int n = n0 + j * 16 + r;
    const int m = m0 + wv * 16 + q * 4;
    short4v s1, s2;
#pragma unroll
    for (int t = 0; t < 4; ++t) {
      s1[t] = (short)f2bf(acc1[j][t]);
      s2[t] = (short)f2bf(acc2[j][t]);
    }
    *(short4v*)&P_T[(size_t)y * 65536 + n * DD + m] = s1;
    *(short4v*)&P_T[(size_t)(NSPLIT + y) * 65536 + n * DD + m] = s2;
  }
}

// ---------------------------------------------------------------------------
// K3: G_T[z][n][m] = sum over y of bf16 P. Reads 8 MB, writes 512 KB fp32.
// 128 blocks x 256 thr, each thread 4 floats.
__global__ void reduce_g(const unsigned short* __restrict__ P_T, float* __restrict__ G_T) {
  int idx = blockIdx.x * 256 + threadIdx.x;     // [0, 32768)
  int z = idx >> 14, off = (idx & 16383) * 4;
  floatx4 s = (floatx4){0.f, 0.f, 0.f, 0.f};
#pragma unroll
  for (int y = 0; y < NSPLIT; ++y) {
    short4v v = *(const short4v*)&P_T[(size_t)(z * NSPLIT + y) * 65536 + off];
#pragma unroll
    for (int c = 0; c < 4; ++c) s[c] += bf2f((unsigned short)v[c]);
  }
  *(floatx4*)&G_T[(size_t)z * 65536 + off] = s;
}

// ---------------------------------------------------------------------------
// K4: Ht_z = transpose of H_z, H_z = (G_z/256) @ W3seg_z. 64x64 tiles,
// grid (16,1,2) on L2-hot G_T and W3.
__global__ __launch_bounds__(256, 2)
void h_mfma(const float* __restrict__ G_T, const float* __restrict__ W3,
            unsigned short* __restrict__ H1t, unsigned short* __restrict__ H2t)
{
  __shared__ __align__(16) unsigned short smA[64 * 136];
  __shared__ __align__(16) unsigned short smB[64 * 136];
  const int T = threadIdx.x, lane = T & 63, wv = T >> 6;
  const int q = lane >> 4, r = lane & 15;
  const int z = blockIdx.z;
  const int me0 = (blockIdx.x >> 2) * 64, m30 = (blockIdx.x & 3) * 64;
  const float* G = G_T + (size_t)z * 65536;
  unsigned short* Ht = z ? H2t : H1t;
  const int woff = 256 + z * 256;

  floatx4 acc[4];
#pragma unroll
  for (int j = 0; j < 4; ++j) acc[j] = (floatx4){0.f, 0.f, 0.f, 0.f};

  for (int lc = 0; lc < 256; lc += 128) {
#pragma unroll
    for (int pp = 0; pp < 2; ++pp) {
      const int id = pp * 256 + T, lb = id >> 4, e4 = id & 15;
      floatx4 grow[4], wrow[4];
#pragma unroll
      for (int i = 0; i < 4; ++i) {
        grow[i] = *(const floatx4*)&G[(size_t)(lc + lb * 4 + i) * DD + me0 + e4 * 4];
        wrow[i] = *(const floatx4*)&W3[(size_t)(woff + lc + lb * 4 + i) * DD + m30 + e4 * 4];
      }
#pragma unroll
      for (int s4 = 0; s4 < 4; ++s4) {
        const int c = (s4 + e4) & 3;
        short4v ga = {(short)f2bf(grow[0][c] * 0.00390625f),
                      (short)f2bf(grow[1][c] * 0.00390625f),
                      (short)f2bf(grow[2][c] * 0.00390625f),
                      (short)f2bf(grow[3][c] * 0.00390625f)};
        short4v wa = {(short)f2bf(wrow[0][c]), (short)f2bf(wrow[1][c]),
                      (short)f2bf(wrow[2][c]), (short)f2bf(wrow[3][c])};
        *(short4v*)&smA[(e4 * 4 + c) * 136 + lb * 4] = ga;
        *(short4v*)&smB[(e4 * 4 + c) * 136 + lb * 4] = wa;
      }
    }
    __syncthreads();
#pragma unroll
    for (int ks = 0; ks < 4; ++ks) {
      short8 af = *(const short8*)&smA[(wv * 16 + r) * 136 + ks * 32 + q * 8];
#pragma unroll
      for (int j = 0; j < 4; ++j) {
        short8 bf = *(const short8*)&smB[(j * 16 + r) * 136 + ks * 32 + q * 8];
        acc[j] = mfma_bf16(af, bf, acc[j]);
      }
    }
    __syncthreads();
  }
#pragma unroll
  for (int j = 0; j < 4; ++j) {
    const int m3 = m30 + j * 16 + r;
    const int me = me0 + wv * 16 + q * 4;
    short4v v;
#pragma unroll
    for (int i = 0; i < 4; ++i) v[i] = (short)f2bf(acc[j][i]);
    *(short4v*)&Ht[(size_t)m3 * DD + me] = v;
  }
}

// ---------------------------------------------------------------------------
// K5: out = relu(xb*W3a + e1*H1 + e2*H2 + b3), fp32 out. Uniform 6-round
// bf16 loop with reg-prefetch. Tile 64x64, 512 blocks 1-D, XCD-affine.
__global__ __launch_bounds__(256, 4)
void out_gemm(const unsigned short* __restrict__ xb,
              const unsigned short* __restrict__ e1, const unsigned short* __restrict__ e2,
              const unsigned short* __restrict__ W3t0,
              const unsigned short* __restrict__ H1t, const unsigned short* __restrict__ H2t,
              const float* __restrict__ b3, float* __restrict__ out)
{
  __shared__ __align__(16) unsigned short smA[64 * 136];
  __shared__ __align__(16) unsigned short smB[64 * 136];
  const int T = threadIdx.x, lane = T & 63, wv = T >> 6;
  const int q = lane >> 4, r = lane & 15;
  const int L = blockIdx.x;
  const int p = L & 7, k = L >> 3;
  const int col0 = (k & 3) * 64, row0 = (16 * p + (k >> 2)) * 64;

  const unsigned short* As[3] = {xb, e1, e2};
  const unsigned short* Bs[3] = {W3t0, H1t, H2t};

  floatx4 acc[4];
#pragma unroll
  for (int j = 0; j < 4; ++j) acc[j] = (floatx4){0.f, 0.f, 0.f, 0.f};

  short8 qa[4], qb[4];
#pragma unroll
  for (int pp = 0; pp < 4; ++pp) {
    const int id = pp * 256 + T, rr = id >> 4, k8 = (id & 15) * 8;
    qa[pp] = *(const short8*)&As[0][(size_t)(row0 + rr) * DD + k8];
    qb[pp] = *(const short8*)&Bs[0][(size_t)(col0 + rr) * DD + k8];
  }

  for (int rd = 0; rd < 6; ++rd) {
#pragma unroll
    for (int pp = 0; pp < 4; ++pp) {
      const int id = pp * 256 + T, rr = id >> 4, k8 = (id & 15) * 8;
      *(short8*)&smA[rr * 136 + k8] = qa[pp];
      *(short8*)&smB[rr * 136 + k8] = qb[pp];
    }
    __syncthreads();
    if (rd + 1 < 6) {
      const int s = (rd + 1) >> 1, kc = ((rd + 1) & 1) * 128;
      const unsigned short* A = As[s];
      const unsigned short* B = Bs[s];
#pragma unroll
      for (int pp = 0; pp < 4; ++pp) {
        const int id = pp * 256 + T, rr = id >> 4, k8 = (id & 15) * 8;
        qa[pp] = *(const short8*)&A[(size_t)(row0 + rr) * DD + kc + k8];
        qb[pp] = *(const short8*)&B[(size_t)(col0 + rr) * DD + kc + k8];
      }
    }
#pragma unroll
    for (int ks = 0; ks < 4; ++ks) {
      short8 af = *(const short8*)&smA[(wv * 16 + r) * 136 + ks * 32 + q * 8];
#pragma unroll
      for (int j = 0; j < 4; ++j) {
        short8 bf = *(const short8*)&smB[(j * 16 + r) * 136 + ks * 32 + q * 8];
        acc[j] = mfma_bf16(af, bf, acc[j]);
      }
    }
    __syncthreads();
  }
#pragma unroll
  for (int j = 0; j < 4; ++j) {
    const int col = col0 + j * 16 + r;
    const float bv = b3[col];
    const int rowb = row0 + wv * 16 + q * 4;
#pragma unroll
    for (int t = 0; t < 4; ++t)
      out[(size_t)(rowb + t) * DD + col] = fmaxf(acc[j][t] + bv, 0.0f);
  }
}

// ---------------------------------------------------------------------------
extern "C" void kernel_launch(void* const* d_in, const int* in_sizes, int n_in,
                              void* d_out, int out_size, void* d_ws, size_t ws_size,
                              hipStream_t stream) {
  (void)in_sizes; (void)n_in; (void)out_size; (void)ws_size;
  const float* x  = (const float*)d_in[3];
  const float* W1 = (const float*)d_in[5];
  const float* b1 = (const float*)d_in[6];
  const float* W2 = (const float*)d_in[7];
  const float* b2 = (const float*)d_in[8];
  const float* W3 = (const float*)d_in[9];
  const float* b3 = (const float*)d_in[10];
  float* out = (float*)d_out;

  char* ws = (char*)d_ws;
  const size_t MB = 1u << 20;
  const size_t KB = 1u << 10;
  unsigned short* xb   = (unsigned short*)ws;                          // 4 MB
  unsigned short* xT   = (unsigned short*)(ws + 4 * MB);               // 4 MB
  unsigned short* e1   = (unsigned short*)(ws + 8 * MB);               // 4 MB
  unsigned short* e2   = (unsigned short*)(ws + 12 * MB);              // 4 MB
  unsigned short* e1T  = (unsigned short*)(ws + 16 * MB);              // 4 MB
  unsigned short* e2T  = (unsigned short*)(ws + 20 * MB);              // 4 MB
  unsigned short* W1t  = (unsigned short*)(ws + 24 * MB);              // 128 KB
  unsigned short* W2t  = (unsigned short*)(ws + 24 * MB + 128 * KB);   // 128 KB
  unsigned short* W3t0 = (unsigned short*)(ws + 24 * MB + 256 * KB);   // 128 KB
  unsigned short* H1t  = (unsigned short*)(ws + 24 * MB + 384 * KB);   // 128 KB
  unsigned short* H2t  = (unsigned short*)(ws + 24 * MB + 512 * KB);   // 128 KB
  float* G_T           = (float*)(ws + 24 * MB + 640 * KB);            // 512 KB
  unsigned short* P_T  = (unsigned short*)(ws + 25 * MB);              // 8 MB (bf16, 64 slices)

  cvt_all<<<560, 256, 0, stream>>>(x, xb, xT, W1, W1t, W2, W2t, W3, W3t0);
  e_gemm<<<512, 256, 0, stream>>>(xb, W1t, b1, W2t, b2, e1, e2, e1T, e2T);
  atb<<<512, 256, 0, stream>>>(e1T, e2T, xT, P_T);
  reduce_g<<<128, 256, 0, stream>>>(P_T, G_T);
  h_mfma<<<dim3(16, 1, 2), 256, 0, stream>>>(G_T, W3, H1t, H2t);
  out_gemm<<<512, 256, 0, stream>>>(xb, e1, e2, W3t0, H1t, H2t, b3, out);
}